// Round 20
// baseline (115.357 us; speedup 1.0000x reference)
//
#include <hip/hip_runtime.h>
#include <hip/hip_bf16.h>

typedef unsigned short u16;
typedef unsigned int u32;
typedef __attribute__((ext_vector_type(8))) short bf16x8;   // 8 bf16 (4 VGPRs)
typedef __attribute__((ext_vector_type(8))) u16 u16x8;
typedef __attribute__((ext_vector_type(4))) u16 u16x4;
typedef __attribute__((ext_vector_type(2))) u32 u32x2;
typedef __attribute__((ext_vector_type(4))) u32 u32x4;
typedef __attribute__((ext_vector_type(4))) float f32x4;
typedef __attribute__((ext_vector_type(4))) _Float16 f16x4;
typedef __attribute__((ext_vector_type(8))) _Float16 f16x8;
typedef __attribute__((ext_vector_type(16))) float f32x16;

typedef const __attribute__((address_space(1))) void* gas1_t;
typedef __attribute__((address_space(3))) void* las3_t;

#define MFMA16(a,b,c) __builtin_amdgcn_mfma_f32_16x16x32_bf16((a),(b),(c),0,0,0)
#define MFMA32(a,b,c) __builtin_amdgcn_mfma_f32_32x32x16_bf16((a),(b),(c),0,0,0)

static constexpr int BB = 4, SS = 1024, DD = 1024, HH = 16;

static __device__ __forceinline__ u16 f2b(float x) {
  union { __hip_bfloat16 h; u16 u; } cv;
  cv.h = __float2bfloat16(x);
  return cv.u;
}
static __device__ __forceinline__ u32 pk2(float a, float b) {
  return (u32)f2b(a) | ((u32)f2b(b) << 16);
}
// packed f32x2 -> bf16x2 (RNE), src0 -> low16 (round-3-proven instruction)
static __device__ __forceinline__ u32 cvtpk(float lo, float hi) {
  u32 r;
  asm("v_cvt_pk_bf16_f32 %0, %1, %2" : "=v"(r) : "v"(lo), "v"(hi));
  return r;
}

// ---------------- fp32 -> bf16 weights + bias pack (activations converted in-GEMM) -------
__global__ __launch_bounds__(256) void cvt_all(
    const float* __restrict__ wq_, const float* __restrict__ wk_, const float* __restrict__ wv_,
    const float* __restrict__ wp_, const float* __restrict__ bias,
    u16* __restrict__ wqb, u16* __restrict__ wkb, u16* __restrict__ wvb, u16* __restrict__ wpb,
    _Float16* __restrict__ bias16) {
  int bid = blockIdx.x;
  if (bid >= 4096) {   // bias pack, granule-per-thread (r13-proven coalesced layout)
    int G = (bid - 4096) * 256 + threadIdx.x;        // granule id, 524288 total
    int gi = G & 1023;
    int ctid = gi & 255, g = gi >> 8;
    int T = G >> 10;                                  // (b*8 + qt)*16 + kt
    int kt = T & 15, qt = (T >> 4) & 7, b_ = T >> 7;
    int wq = ctid >> 6, hi = (ctid >> 5) & 1, ln = ctid & 31;
    int qrow = qt * 128 + wq * 32 + ln;
    int kbf = g >> 1, j = g & 1;
    int k0 = kt * 64 + kbf * 32 + j * 16 + hi * 4;
    const float* src = bias + (((size_t)(b_ * 1024 + qrow)) << 10) + k0;
    float4 lo = *(const float4*)(src);
    float4 up = *(const float4*)(src + 8);
    f16x8 r = { (_Float16)lo.x, (_Float16)lo.y, (_Float16)lo.z, (_Float16)lo.w,
                (_Float16)up.x, (_Float16)up.y, (_Float16)up.z, (_Float16)up.w };
    *(f16x8*)(bias16 + (((size_t)T) << 13) + g * 2048 + ctid * 8) = r;
    return;
  }
  const float* s; u16* d; int off;
  if      (bid < 1024) { s = wq_; d = wqb; off = bid; }
  else if (bid < 2048) { s = wk_; d = wkb; off = bid - 1024; }
  else if (bid < 3072) { s = wv_; d = wvb; off = bid - 2048; }
  else                 { s = wp_; d = wpb; off = bid - 3072; }
  int i = (off * 256 + threadIdx.x) * 4;
  float4 val = *(const float4*)(s + i);
  u16x4 r = { f2b(val.x), f2b(val.y), f2b(val.z), f2b(val.w) };
  *(u16x4*)(d + i) = r;
}

// ---------------- QKV GEMM: double-buffered, ONE barrier per K-step ----------------
// C = cvt(A_fp32) * W_bf16^T. Per step k: issue W(k+1) DMA -> Bs[nxt]; issue A global
// loads (k+2) early; ds_write cvt(regs k+1) -> As[nxt]; compute tile k; one barrier.
// Inner loop = r15-proven bf16 path. LDS 64 KB (2 blocks/CU).
__global__ __launch_bounds__(512) void gemm_qkv(
    const float* __restrict__ Qf, const float* __restrict__ Kf, const float* __restrict__ Vf,
    const u16* __restrict__ Wbase, u16* __restrict__ Qb, u16* __restrict__ Kb,
    u16* __restrict__ Vtb) {
  const int z = blockIdx.z;
  const float* A = z == 0 ? Qf : (z == 1 ? Kf : Vf);
  const u16* W = Wbase + (size_t)z * (DD * DD);

  __shared__ __align__(16) u16 As[2][128 * 64];   // 2x16 KB (bf16)
  __shared__ __align__(16) u16 Bs[2][128 * 64];   // 2x16 KB

  const int tid = threadIdx.x;
  const int lane = tid & 63;
  const int wid = tid >> 6;                 // 0..7
  const int g = lane >> 4;
  const int li = lane & 15;

  const int hw = blockIdx.x + (blockIdx.y << 3);          // 0..255
  const int L = ((hw & 7) << 5) + (hw >> 3);
  const int brow = (L >> 3) * 128;
  const int bcol = (L & 7) * 128;

  const int wr = (wid >> 1) * 32;           // 4 row-strips of 32
  const int wc = (wid & 1) * 64;            // 2 col-strips of 64

  // A reg-staging: issue i covers row i*32 + (tid>>4); fp32 granule tid&15 (coalesced)
  const int arow = tid >> 4;                         // 0..31
  const int ag = tid & 15;
  const float* ga0 = A + (size_t)(brow + arow) * DD + ag * 4;
  const u32 awb = (u32)((((ag >> 1) ^ (arow & 7)) << 4) + ((ag & 1) << 3));  // byte in row

  // W staging (gload_lds): srow = tid>>3, piece = (tid&7)^(srow&7)
  const int srw = tid >> 3;
  const int spw = (tid & 7) ^ (srw & 7);
  const u16* gw0 = W + (size_t)(bcol + srw) * DD + spw * 8;

  f32x4 acc[2][4] = {};
  f32x4 sa[4], sb[4];

  auto loadA = [&](f32x4* S, int kt) {
#pragma unroll
    for (int i = 0; i < 4; ++i)
      S[i] = *(const f32x4*)(ga0 + (size_t)(i * 32) * DD + kt * 64);
  };
  auto stageA = [&](const f32x4* S, u16* dst) {
    char* ab = (char*)dst + arow * 128 + awb;
#pragma unroll
    for (int i = 0; i < 4; ++i) {
      u32x2 w = { cvtpk(S[i][0], S[i][1]), cvtpk(S[i][2], S[i][3]) };
      *(u32x2*)(ab + i * 32 * 128) = w;
    }
  };
  auto stageW = [&](int kt, u16* dst) {
#pragma unroll
    for (int i = 0; i < 2; ++i)
      __builtin_amdgcn_global_load_lds(
          (gas1_t)(const void*)(gw0 + (size_t)(i * 64) * DD + kt * 64),
          (las3_t)(void*)(dst + (i * 64 + (wid << 3)) * 64), 16, 0, 0);
  };
  auto compute = [&](const u16* Asb, const u16* Bsb) {
#pragma unroll
    for (int kk = 0; kk < 2; ++kk) {
      bf16x8 a[2], b[4];
#pragma unroll
      for (int m = 0; m < 2; ++m) {
        int row = wr + m * 16 + li;
        a[m] = *(const bf16x8*)&Asb[row * 64 + (((kk * 4 + g) ^ (li & 7)) << 3)];
      }
#pragma unroll
      for (int n = 0; n < 4; ++n) {
        int row = wc + n * 16 + li;
        b[n] = *(const bf16x8*)&Bsb[row * 64 + (((kk * 4 + g) ^ (li & 7)) << 3)];
      }
#pragma unroll
      for (int m = 0; m < 2; ++m)
#pragma unroll
        for (int n = 0; n < 4; ++n)
          acc[m][n] = MFMA16(a[m], b[n], acc[m][n]);
    }
  };

  // ---- prologue: tile 0 staged (one cold drain), regs(1) in flight ----
  loadA(sa, 0);
  stageW(0, Bs[0]);
  stageA(sa, As[0]);          // waits on sa loads (cold, once)
  loadA(sb, 1);
  __syncthreads();

  // ---- main loop: even/odd steps, one barrier each ----
  for (int k2 = 0; k2 < 16; k2 += 2) {
    {   // k even, cur = 0: write A(k+1) from sb, load regs(k+2) -> sa
      const int k = k2;
      if (k < 15) {
        stageW(k + 1, Bs[1]);
        if (k < 14) loadA(sa, k + 2);
        stageA(sb, As[1]);
      }
      compute(As[0], Bs[0]);
      if (k < 15) __syncthreads();
    }
    {   // k odd, cur = 1: write A(k+1) from sa, load regs(k+2) -> sb
      const int k = k2 + 1;
      if (k < 15) {
        stageW(k + 1, Bs[0]);
        if (k < 14) loadA(sb, k + 2);
        stageA(sa, As[0]);
      }
      compute(As[1], Bs[1]);
      if (k < 15) __syncthreads();
    }
  }

  if (z == 2) {   // V^T write
#pragma unroll
    for (int m = 0; m < 2; ++m) {
#pragma unroll
      for (int n = 0; n < 4; ++n) {
        int c = bcol + wc + n * 16 + li;
        int h_ = c >> 6, dv = c & 63;
        int r0 = brow + wr + m * 16 + g * 4;
        int b_ = r0 >> 10, s0 = r0 & 1023;
        u16x4 val = { f2b(acc[m][n][0]), f2b(acc[m][n][1]),
                      f2b(acc[m][n][2]), f2b(acc[m][n][3]) };
        *(u16x4*)&Vtb[(size_t)((b_ * HH + h_) * 64 + dv) * SS + s0] = val;
      }
    }
  } else {
    u16* C = z == 0 ? Qb : Kb;
#pragma unroll
    for (int m = 0; m < 2; ++m)
#pragma unroll
      for (int n = 0; n < 4; ++n)
#pragma unroll
        for (int j = 0; j < 4; ++j) {
          int r = brow + wr + m * 16 + g * 4 + j;
          int c = bcol + wc + n * 16 + li;
          C[(size_t)r * DD + c] = f2b(acc[m][n][j]);
        }
  }
}

// ---------------- proj GEMM (512 thr / 8 waves, bf16 in, fp32 out) — r15-proven ----------------
__global__ __launch_bounds__(512) void gemm_proj(
    const u16* __restrict__ A, const u16* __restrict__ W, float* __restrict__ C,
    int N, int K) {
  __shared__ __align__(16) u16 As[128 * 64];
  __shared__ __align__(16) u16 Bs[128 * 64];

  const int tid = threadIdx.x;
  const int lane = tid & 63;
  const int wid = tid >> 6;
  const int g = lane >> 4;
  const int li = lane & 15;

  const int hw = blockIdx.x + (blockIdx.y << 3);
  const int L = ((hw & 7) << 5) + (hw >> 3);
  const int brow = (L >> 3) * 128;
  const int bcol = (L & 7) * 128;

  const int wr = (wid >> 1) * 32;
  const int wc = (wid & 1) * 64;

  const int srow = tid >> 3;
  const int schunk = (tid & 7) ^ (srow & 7);
  const u16* ga0 = A + (size_t)(brow + srow) * K + schunk * 8;
  const u16* gw0 = W + (size_t)(bcol + srow) * K + schunk * 8;

  f32x4 acc[2][4] = {};

  for (int k0 = 0; k0 < K; k0 += 64) {
#pragma unroll
    for (int i = 0; i < 2; ++i) {
      __builtin_amdgcn_global_load_lds((gas1_t)(const void*)(ga0 + (size_t)(i * 64) * K + k0),
                                       (las3_t)(void*)(As + (i * 64 + (wid << 3)) * 64), 16, 0, 0);
      __builtin_amdgcn_global_load_lds((gas1_t)(const void*)(gw0 + (size_t)(i * 64) * K + k0),
                                       (las3_t)(void*)(Bs + (i * 64 + (wid << 3)) * 64), 16, 0, 0);
    }
    __syncthreads();

#pragma unroll
    for (int kk = 0; kk < 2; ++kk) {
      bf16x8 a[2], b[4];
#pragma unroll
      for (int m = 0; m < 2; ++m) {
        int row = wr + m * 16 + li;
        a[m] = *(const bf16x8*)&As[row * 64 + (((kk * 4 + g) ^ (li & 7)) << 3)];
      }
#pragma unroll
      for (int n = 0; n < 4; ++n) {
        int row = wc + n * 16 + li;
        b[n] = *(const bf16x8*)&Bs[row * 64 + (((kk * 4 + g) ^ (li & 7)) << 3)];
      }
#pragma unroll
      for (int m = 0; m < 2; ++m)
#pragma unroll
        for (int n = 0; n < 4; ++n)
          acc[m][n] = MFMA16(a[m], b[n], acc[m][n]);
    }
    __syncthreads();
  }

#pragma unroll
  for (int m = 0; m < 2; ++m)
#pragma unroll
    for (int n = 0; n < 4; ++n)
#pragma unroll
      for (int j = 0; j < 4; ++j) {
        int r = brow + wr + m * 16 + g * 4 + j;
        int c = bcol + wc + n * 16 + li;
        C[(size_t)r * N + c] = acc[m][n][j];
      }
}

// ---------------- fused flash attention (r13 body, UNCHANGED — confirmed floor) ----------------
__global__ __launch_bounds__(256) void attn_kernel(
    const u16* __restrict__ Q, const u16* __restrict__ K, const u16* __restrict__ Vt,
    const _Float16* __restrict__ bias16, u16* __restrict__ O) {
  __shared__ __align__(16) u16 kbuf[2][64 * 64];
  __shared__ __align__(16) u16 vbuf[2][64 * 64];

  const int tid = threadIdx.x;
  const int lane = tid & 63;
  const int wq = tid >> 6;
  const int hi = lane >> 5;
  const int ln = lane & 31;
  const u32 swz = (u32)(ln & 7) << 4;

  const int flat = blockIdx.x + (blockIdx.y << 3) + (blockIdx.z << 7);
  const int L = ((flat & 7) << 6) | (flat >> 3);
  const int qt = L & 7, h = (L >> 3) & 15, b = L >> 7;
  const int q0 = qt * 128;
  const int qrow = q0 + wq * 32 + ln;

  bf16x8 qf[4];
  {
    const u16* qp = Q + (size_t)(b * SS + qrow) * DD + h * 64 + hi * 8;
#pragma unroll
    for (int d = 0; d < 4; ++d) qf[d] = *(const bf16x8*)(qp + d * 16);
  }

  const int srow = (lane >> 3);
  const int spc = ((lane & 7) ^ srow) * 8;
  const u16* kgl = K + (size_t)(b * SS + wq * 16 + srow) * DD + h * 64 + spc;
  const u16* vgl = Vt + (size_t)((b * HH + h) * 64 + wq * 16 + srow) * SS + spc;

  const _Float16* btile = bias16 + (((size_t)(b * 8 + qt) * 16) << 13) + tid * 8;

  {
    char* kd = (char*)kbuf[0] + wq * 2048;
    char* vd = (char*)vbuf[0] + wq * 2048;
#pragma unroll
    for (int j = 0; j < 2; ++j) {
      __builtin_amdgcn_global_load_lds((gas1_t)(const void*)(kgl + (size_t)(j * 8) * DD),
                                       (las3_t)(void*)(kd + j * 1024), 16, 0, 0);
      __builtin_amdgcn_global_load_lds((gas1_t)(const void*)(vgl + (size_t)(j * 8) * SS),
                                       (las3_t)(void*)(vd + j * 1024), 16, 0, 0);
    }
  }
  f16x8 bbr[4], bbn[4];
#pragma unroll
  for (int g = 0; g < 4; ++g)
    bbr[g] = *(const f16x8*)(btile + g * 2048);
  __syncthreads();

  f32x16 o0 = {}, o1 = {};
  float m = -1e30f, lsum = 0.f;
  int cur = 0;

  for (int kt = 0; kt < 16; ++kt) {
    if (kt < 15) {
      char* kd = (char*)kbuf[cur ^ 1] + wq * 2048;
      char* vd = (char*)vbuf[cur ^ 1] + wq * 2048;
      const size_t k1 = (size_t)(kt + 1) * 64;
#pragma unroll
      for (int j = 0; j < 2; ++j) {
        __builtin_amdgcn_global_load_lds((gas1_t)(const void*)(kgl + (k1 + j * 8) * DD),
                                         (las3_t)(void*)(kd + j * 1024), 16, 0, 0);
        __builtin_amdgcn_global_load_lds((gas1_t)(const void*)(vgl + (size_t)(j * 8) * SS + k1),
                                         (las3_t)(void*)(vd + j * 1024), 16, 0, 0);
      }
      const _Float16* bt = btile + ((size_t)(kt + 1) << 13);
#pragma unroll
      for (int g = 0; g < 4; ++g)
        bbn[g] = *(const f16x8*)(bt + g * 2048);
    }

    const char* kb_base = (const char*)kbuf[cur];
    f32x16 s[2];
#pragma unroll
    for (int kb = 0; kb < 2; ++kb) {
      f32x16 acc = {};
#pragma unroll
      for (int d = 0; d < 4; ++d) {
        bf16x8 kf = *(const bf16x8*)(kb_base + (kb * 32 + ln) * 128 + (((u32)(d * 32 + hi * 16)) ^ swz));
        acc = MFMA32(kf, qf[d], acc);
      }
      s[kb] = acc;
    }

#pragma unroll
    for (int g = 0; g < 4; ++g) {
      const int kb = g >> 1, rq0 = (g & 1) * 2;
#pragma unroll
      for (int e = 0; e < 8; ++e)
        s[kb][(rq0 + (e >> 2)) * 4 + (e & 3)] =
            fmaf(s[kb][(rq0 + (e >> 2)) * 4 + (e & 3)], 0.03125f, (float)bbr[g][e]);
    }

    float mt = -1e30f;
#pragma unroll
    for (int r = 0; r < 16; ++r) { mt = fmaxf(mt, s[0][r]); mt = fmaxf(mt, s[1][r]); }
    mt = fmaxf(mt, __shfl_xor(mt, 32));

    bool resc = false;
    float fsc = 1.f;
    if (kt == 0) {
      m = mt;
    } else if (__any(mt > m + 8.f)) {
      float mn = fmaxf(m, mt);
      fsc = __expf(m - mn);
      m = mn;
      resc = true;
    }

    float rs = 0.f;
    u32 wv[2][8];
#pragma unroll
    for (int kb = 0; kb < 2; ++kb)
#pragma unroll
      for (int t = 0; t < 8; ++t) {
        float p0 = __expf(s[kb][2 * t] - m);
        float p1 = __expf(s[kb][2 * t + 1] - m);
        rs += p0 + p1;
        wv[kb][t] = pk2(p0, p1);
      }
    rs += __shfl_xor(rs, 32);
    lsum = lsum * fsc + rs;

    if (resc) {
#pragma unroll
      for (int j = 0; j < 16; ++j) {
        float fv = __shfl(fsc, (j & 3) + 8 * (j >> 2) + 4 * hi);
        o0[j] *= fv; o1[j] *= fv;
      }
    }

    const char* vb_base = (const char*)vbuf[cur];
#pragma unroll
    for (int ks = 0; ks < 4; ++ks) {
      const int kb = ks >> 1, i0 = (ks & 1) * 4;
      u32 sA = hi ? wv[kb][i0 + 0] : wv[kb][i0 + 2];
      u32 sB = hi ? wv[kb][i0 + 1] : wv[kb][i0 + 3];
      u32 rA = (u32)__shfl_xor((int)sA, 32);
      u32 rB = (u32)__shfl_xor((int)sB, 32);
      u32 e0 = hi ? rA : wv[kb][i0 + 0];
      u32 e1 = hi ? rB : wv[kb][i0 + 1];
      u32 e2 = hi ? wv[kb][i0 + 2] : rA;
      u32 e3 = hi ? wv[kb][i0 + 3] : rB;
      union { u32x4 u; bf16x8 v; } pc;
      pc.u = (u32x4){e0, e1, e2, e3};
      bf16x8 pa = pc.v;
#pragma unroll
      for (int nv = 0; nv < 2; ++nv) {
        bf16x8 vf = *(const bf16x8*)(vb_base + (nv * 32 + ln) * 128 + (((u32)(ks * 32 + hi * 16)) ^ swz));
        if (nv == 0) o0 = MFMA32(pa, vf, o0);
        else         o1 = MFMA32(pa, vf, o1);
      }
    }

    if (kt < 15) {
      __syncthreads();
      cur ^= 1;
#pragma unroll
      for (int g = 0; g < 4; ++g) bbr[g] = bbn[g];
    }
  }

  float inv = 1.0f / lsum;
#pragma unroll
  for (int j = 0; j < 16; ++j) {
    float iv = __shfl(inv, (j & 3) + 8 * (j >> 2) + 4 * hi);
    int q = q0 + wq * 32 + (j & 3) + 8 * (j >> 2) + 4 * hi;
    u16* op = O + (size_t)(b * SS + q) * DD + h * 64 + ln;
    op[0]  = f2b(o0[j] * iv);
    op[32] = f2b(o1[j] * iv);
  }
}

// ---------------- host launch ----------------
extern "C" void kernel_launch(void* const* d_in, const int* in_sizes, int n_in,
                              void* d_out, int out_size, void* d_ws, size_t ws_size,
                              hipStream_t stream) {
  const float* queries = (const float*)d_in[0];
  const float* keys    = (const float*)d_in[1];
  const float* values  = (const float*)d_in[2];
  const float* bias    = (const float*)d_in[3];
  const float* Wq      = (const float*)d_in[4];
  const float* Wk      = (const float*)d_in[5];
  const float* Wv      = (const float*)d_in[6];
  const float* Wp      = (const float*)d_in[7];
  float* out = (float*)d_out;

  char* ws = (char*)d_ws;
  const size_t MB = 1024 * 1024;
  u16* wqb = (u16*)(ws + 24 * MB);   // wqb/wkb/wvb contiguous at 2 MB stride
  u16* wkb = (u16*)(ws + 26 * MB);
  u16* wvb = (u16*)(ws + 28 * MB);
  u16* wpb = (u16*)(ws + 30 * MB);
  u16* Qb  = (u16*)(ws + 32 * MB);
  u16* Kb  = (u16*)(ws + 40 * MB);
  _Float16* bias16 = (_Float16*)(ws + 48 * MB);
  u16* Vtb = (u16*)(ws + 56 * MB);
  u16* Ob  = (u16*)(ws + 0 * MB);

  // weights + bias pack
  cvt_all<<<dim3(6144), dim3(256), 0, stream>>>(
      Wq, Wk, Wv, Wp, bias, wqb, wkb, wvb, wpb, bias16);

  // QKV projections: double-buffered single-barrier, reg-staged fp32 A -> bf16 LDS
  gemm_qkv<<<dim3(8, 32, 3), dim3(512), 0, stream>>>(
      queries, keys, values, wqb, Qb, Kb, Vtb);

  attn_kernel<<<dim3(8, 16, 4), dim3(256), 0, stream>>>(Qb, Kb, Vtb, bias16, Ob);

  gemm_proj<<<dim3(8, 32, 1), dim3(512), 0, stream>>>(Ob, wpb, out, DD, DD);
}

// Round 21
// 111.872 us; speedup vs baseline: 1.0312x; 1.0312x over previous
//
#include <hip/hip_runtime.h>
#include <hip/hip_bf16.h>

typedef unsigned short u16;
typedef unsigned int u32;
typedef __attribute__((ext_vector_type(8))) short bf16x8;   // 8 bf16 (4 VGPRs)
typedef __attribute__((ext_vector_type(8))) u16 u16x8;
typedef __attribute__((ext_vector_type(4))) u16 u16x4;
typedef __attribute__((ext_vector_type(2))) u32 u32x2;
typedef __attribute__((ext_vector_type(4))) u32 u32x4;
typedef __attribute__((ext_vector_type(4))) float f32x4;
typedef __attribute__((ext_vector_type(4))) _Float16 f16x4;
typedef __attribute__((ext_vector_type(8))) _Float16 f16x8;
typedef __attribute__((ext_vector_type(16))) float f32x16;

typedef const __attribute__((address_space(1))) void* gas1_t;
typedef __attribute__((address_space(3))) void* las3_t;

#define MFMA16(a,b,c) __builtin_amdgcn_mfma_f32_16x16x32_bf16((a),(b),(c),0,0,0)
#define MFMA32(a,b,c) __builtin_amdgcn_mfma_f32_32x32x16_bf16((a),(b),(c),0,0,0)

static constexpr int BB = 4, SS = 1024, DD = 1024, HH = 16;

static __device__ __forceinline__ u16 f2b(float x) {
  union { __hip_bfloat16 h; u16 u; } cv;
  cv.h = __float2bfloat16(x);
  return cv.u;
}
static __device__ __forceinline__ u32 pk2(float a, float b) {
  return (u32)f2b(a) | ((u32)f2b(b) << 16);
}
// packed f32x2 -> bf16x2 (RNE), src0 -> low16 (round-3-proven instruction)
static __device__ __forceinline__ u32 cvtpk(float lo, float hi) {
  u32 r;
  asm("v_cvt_pk_bf16_f32 %0, %1, %2" : "=v"(r) : "v"(lo), "v"(hi));
  return r;
}

// ---------------- fp32 -> bf16 weights + bias pack (activations converted in-GEMM) -------
__global__ __launch_bounds__(256) void cvt_all(
    const float* __restrict__ wq_, const float* __restrict__ wk_, const float* __restrict__ wv_,
    const float* __restrict__ wp_, const float* __restrict__ bias,
    u16* __restrict__ wqb, u16* __restrict__ wkb, u16* __restrict__ wvb, u16* __restrict__ wpb,
    _Float16* __restrict__ bias16) {
  int bid = blockIdx.x;
  if (bid >= 4096) {   // bias pack, granule-per-thread (r13-proven coalesced layout)
    int G = (bid - 4096) * 256 + threadIdx.x;        // granule id, 524288 total
    int gi = G & 1023;
    int ctid = gi & 255, g = gi >> 8;
    int T = G >> 10;                                  // (b*8 + qt)*16 + kt
    int kt = T & 15, qt = (T >> 4) & 7, b_ = T >> 7;
    int wq = ctid >> 6, hi = (ctid >> 5) & 1, ln = ctid & 31;
    int qrow = qt * 128 + wq * 32 + ln;
    int kbf = g >> 1, j = g & 1;
    int k0 = kt * 64 + kbf * 32 + j * 16 + hi * 4;
    const float* src = bias + (((size_t)(b_ * 1024 + qrow)) << 10) + k0;
    float4 lo = *(const float4*)(src);
    float4 up = *(const float4*)(src + 8);
    f16x8 r = { (_Float16)lo.x, (_Float16)lo.y, (_Float16)lo.z, (_Float16)lo.w,
                (_Float16)up.x, (_Float16)up.y, (_Float16)up.z, (_Float16)up.w };
    *(f16x8*)(bias16 + (((size_t)T) << 13) + g * 2048 + ctid * 8) = r;
    return;
  }
  const float* s; u16* d; int off;
  if      (bid < 1024) { s = wq_; d = wqb; off = bid; }
  else if (bid < 2048) { s = wk_; d = wkb; off = bid - 1024; }
  else if (bid < 3072) { s = wv_; d = wvb; off = bid - 2048; }
  else                 { s = wp_; d = wpb; off = bid - 3072; }
  int i = (off * 256 + threadIdx.x) * 4;
  float4 val = *(const float4*)(s + i);
  u16x4 r = { f2b(val.x), f2b(val.y), f2b(val.z), f2b(val.w) };
  *(u16x4*)(d + i) = r;
}

// ---------------- QKV GEMM (512 thr / 8 waves): reg-staged fp32 A -> cvt -> bf16 LDS --------
// C[M,N] = cvt(A[M,K]) * W[N,K]^T. Inner loop is r15's PROVEN bf16 path (As 16 KB,
// chunk^(row&7) swizzle). A: 4 coalesced dwordx4/thread -> 8 cvtpk -> 4 ds_write_b64
// (each row's 16 writes cover all 32 banks once). A loads for k+1 prefetched into regs
// before the compute barrier -> full-tile latency cover. Only W's 16 KB DMA drains.
__global__ __launch_bounds__(512) void gemm_qkv(
    const float* __restrict__ Qf, const float* __restrict__ Kf, const float* __restrict__ Vf,
    const u16* __restrict__ Wbase, u16* __restrict__ Qb, u16* __restrict__ Kb,
    u16* __restrict__ Vtb) {
  const int z = blockIdx.z;
  const float* A = z == 0 ? Qf : (z == 1 ? Kf : Vf);
  const u16* W = Wbase + (size_t)z * (DD * DD);

  __shared__ __align__(16) u16 As[128 * 64];     // 16 KB (bf16)
  __shared__ __align__(16) u16 Bs[128 * 64];     // 16 KB

  const int tid = threadIdx.x;
  const int lane = tid & 63;
  const int wid = tid >> 6;                 // 0..7
  const int g = lane >> 4;
  const int li = lane & 15;

  const int hw = blockIdx.x + (blockIdx.y << 3);          // 0..255
  const int L = ((hw & 7) << 5) + (hw >> 3);
  const int brow = (L >> 3) * 128;
  const int bcol = (L & 7) * 128;

  const int wr = (wid >> 1) * 32;           // 4 row-strips of 32
  const int wc = (wid & 1) * 64;            // 2 col-strips of 64

  // A reg-staging: issue i covers row i*32 + (tid>>4); fp32 granule tid&15 (coalesced)
  const int arow = tid >> 4;                         // 0..31
  const int ag = tid & 15;
  const float* ga0 = A + (size_t)(brow + arow) * DD + ag * 4;
  const u32 awb = (u32)((((ag >> 1) ^ (arow & 7)) << 4) + ((ag & 1) << 3));  // byte in row

  // W staging (gload_lds, r15-proven): srow = tid>>3, piece = (tid&7)^(srow&7)
  const int srw = tid >> 3;
  const int spw = (tid & 7) ^ (srw & 7);
  const u16* gw0 = W + (size_t)(bcol + srw) * DD + spw * 8;

  f32x4 acc[2][4] = {};

  // prologue: A fp32 regs for k0 = 0
  f32x4 ar0 = *(const f32x4*)(ga0 + (size_t)(0 * 32) * DD);
  f32x4 ar1 = *(const f32x4*)(ga0 + (size_t)(1 * 32) * DD);
  f32x4 ar2 = *(const f32x4*)(ga0 + (size_t)(2 * 32) * DD);
  f32x4 ar3 = *(const f32x4*)(ga0 + (size_t)(3 * 32) * DD);

  for (int k0 = 0; k0 < DD; k0 += 64) {
    // W async -> LDS
#pragma unroll
    for (int i = 0; i < 2; ++i)
      __builtin_amdgcn_global_load_lds((gas1_t)(const void*)(gw0 + (size_t)(i * 64) * DD + k0),
                                       (las3_t)(void*)(Bs + (i * 64 + (wid << 3)) * 64), 16, 0, 0);
    // cvt A regs -> bf16 LDS (swizzled write)
    {
      u32x2 w0 = { cvtpk(ar0[0], ar0[1]), cvtpk(ar0[2], ar0[3]) };
      u32x2 w1 = { cvtpk(ar1[0], ar1[1]), cvtpk(ar1[2], ar1[3]) };
      u32x2 w2 = { cvtpk(ar2[0], ar2[1]), cvtpk(ar2[2], ar2[3]) };
      u32x2 w3 = { cvtpk(ar3[0], ar3[1]), cvtpk(ar3[2], ar3[3]) };
      char* ab = (char*)As + arow * 128 + awb;
      *(u32x2*)(ab + 0 * 32 * 128) = w0;
      *(u32x2*)(ab + 1 * 32 * 128) = w1;
      *(u32x2*)(ab + 2 * 32 * 128) = w2;
      *(u32x2*)(ab + 3 * 32 * 128) = w3;
    }
    // prefetch A for next k-step (lands during compute below)
    if (k0 < DD - 64) {
      ar0 = *(const f32x4*)(ga0 + (size_t)(0 * 32) * DD + k0 + 64);
      ar1 = *(const f32x4*)(ga0 + (size_t)(1 * 32) * DD + k0 + 64);
      ar2 = *(const f32x4*)(ga0 + (size_t)(2 * 32) * DD + k0 + 64);
      ar3 = *(const f32x4*)(ga0 + (size_t)(3 * 32) * DD + k0 + 64);
    }
    __syncthreads();

    // r15-proven bf16 inner loop
#pragma unroll
    for (int kk = 0; kk < 2; ++kk) {
      bf16x8 a[2], b[4];
#pragma unroll
      for (int m = 0; m < 2; ++m) {
        int row = wr + m * 16 + li;
        a[m] = *(const bf16x8*)&As[row * 64 + (((kk * 4 + g) ^ (li & 7)) << 3)];
      }
#pragma unroll
      for (int n = 0; n < 4; ++n) {
        int row = wc + n * 16 + li;
        b[n] = *(const bf16x8*)&Bs[row * 64 + (((kk * 4 + g) ^ (li & 7)) << 3)];
      }
#pragma unroll
      for (int m = 0; m < 2; ++m)
#pragma unroll
        for (int n = 0; n < 4; ++n)
          acc[m][n] = MFMA16(a[m], b[n], acc[m][n]);
    }
    __syncthreads();
  }

  if (z == 2) {   // V^T write
#pragma unroll
    for (int m = 0; m < 2; ++m) {
#pragma unroll
      for (int n = 0; n < 4; ++n) {
        int c = bcol + wc + n * 16 + li;
        int h_ = c >> 6, dv = c & 63;
        int r0 = brow + wr + m * 16 + g * 4;
        int b_ = r0 >> 10, s0 = r0 & 1023;
        u16x4 val = { f2b(acc[m][n][0]), f2b(acc[m][n][1]),
                      f2b(acc[m][n][2]), f2b(acc[m][n][3]) };
        *(u16x4*)&Vtb[(size_t)((b_ * HH + h_) * 64 + dv) * SS + s0] = val;
      }
    }
  } else {
    u16* C = z == 0 ? Qb : Kb;
#pragma unroll
    for (int m = 0; m < 2; ++m)
#pragma unroll
      for (int n = 0; n < 4; ++n)
#pragma unroll
        for (int j = 0; j < 4; ++j) {
          int r = brow + wr + m * 16 + g * 4 + j;
          int c = bcol + wc + n * 16 + li;
          C[(size_t)r * DD + c] = f2b(acc[m][n][j]);
        }
  }
}

// ---------------- proj GEMM (512 thr / 8 waves, bf16 in, fp32 out) — r15-proven ----------------
__global__ __launch_bounds__(512) void gemm_proj(
    const u16* __restrict__ A, const u16* __restrict__ W, float* __restrict__ C,
    int N, int K) {
  __shared__ __align__(16) u16 As[128 * 64];
  __shared__ __align__(16) u16 Bs[128 * 64];

  const int tid = threadIdx.x;
  const int lane = tid & 63;
  const int wid = tid >> 6;
  const int g = lane >> 4;
  const int li = lane & 15;

  const int hw = blockIdx.x + (blockIdx.y << 3);
  const int L = ((hw & 7) << 5) + (hw >> 3);
  const int brow = (L >> 3) * 128;
  const int bcol = (L & 7) * 128;

  const int wr = (wid >> 1) * 32;
  const int wc = (wid & 1) * 64;

  const int srow = tid >> 3;
  const int schunk = (tid & 7) ^ (srow & 7);
  const u16* ga0 = A + (size_t)(brow + srow) * K + schunk * 8;
  const u16* gw0 = W + (size_t)(bcol + srow) * K + schunk * 8;

  f32x4 acc[2][4] = {};

  for (int k0 = 0; k0 < K; k0 += 64) {
#pragma unroll
    for (int i = 0; i < 2; ++i) {
      __builtin_amdgcn_global_load_lds((gas1_t)(const void*)(ga0 + (size_t)(i * 64) * K + k0),
                                       (las3_t)(void*)(As + (i * 64 + (wid << 3)) * 64), 16, 0, 0);
      __builtin_amdgcn_global_load_lds((gas1_t)(const void*)(gw0 + (size_t)(i * 64) * K + k0),
                                       (las3_t)(void*)(Bs + (i * 64 + (wid << 3)) * 64), 16, 0, 0);
    }
    __syncthreads();

#pragma unroll
    for (int kk = 0; kk < 2; ++kk) {
      bf16x8 a[2], b[4];
#pragma unroll
      for (int m = 0; m < 2; ++m) {
        int row = wr + m * 16 + li;
        a[m] = *(const bf16x8*)&As[row * 64 + (((kk * 4 + g) ^ (li & 7)) << 3)];
      }
#pragma unroll
      for (int n = 0; n < 4; ++n) {
        int row = wc + n * 16 + li;
        b[n] = *(const bf16x8*)&Bs[row * 64 + (((kk * 4 + g) ^ (li & 7)) << 3)];
      }
#pragma unroll
      for (int m = 0; m < 2; ++m)
#pragma unroll
        for (int n = 0; n < 4; ++n)
          acc[m][n] = MFMA16(a[m], b[n], acc[m][n]);
    }
    __syncthreads();
  }

#pragma unroll
  for (int m = 0; m < 2; ++m)
#pragma unroll
    for (int n = 0; n < 4; ++n)
#pragma unroll
      for (int j = 0; j < 4; ++j) {
        int r = brow + wr + m * 16 + g * 4 + j;
        int c = bcol + wc + n * 16 + li;
        C[(size_t)r * N + c] = acc[m][n][j];
      }
}

// ---------------- fused flash attention (r13 body, UNCHANGED — confirmed floor) ----------------
__global__ __launch_bounds__(256) void attn_kernel(
    const u16* __restrict__ Q, const u16* __restrict__ K, const u16* __restrict__ Vt,
    const _Float16* __restrict__ bias16, u16* __restrict__ O) {
  __shared__ __align__(16) u16 kbuf[2][64 * 64];
  __shared__ __align__(16) u16 vbuf[2][64 * 64];

  const int tid = threadIdx.x;
  const int lane = tid & 63;
  const int wq = tid >> 6;
  const int hi = lane >> 5;
  const int ln = lane & 31;
  const u32 swz = (u32)(ln & 7) << 4;

  const int flat = blockIdx.x + (blockIdx.y << 3) + (blockIdx.z << 7);
  const int L = ((flat & 7) << 6) | (flat >> 3);
  const int qt = L & 7, h = (L >> 3) & 15, b = L >> 7;
  const int q0 = qt * 128;
  const int qrow = q0 + wq * 32 + ln;

  bf16x8 qf[4];
  {
    const u16* qp = Q + (size_t)(b * SS + qrow) * DD + h * 64 + hi * 8;
#pragma unroll
    for (int d = 0; d < 4; ++d) qf[d] = *(const bf16x8*)(qp + d * 16);
  }

  const int srow = (lane >> 3);
  const int spc = ((lane & 7) ^ srow) * 8;
  const u16* kgl = K + (size_t)(b * SS + wq * 16 + srow) * DD + h * 64 + spc;
  const u16* vgl = Vt + (size_t)((b * HH + h) * 64 + wq * 16 + srow) * SS + spc;

  const _Float16* btile = bias16 + (((size_t)(b * 8 + qt) * 16) << 13) + tid * 8;

  {
    char* kd = (char*)kbuf[0] + wq * 2048;
    char* vd = (char*)vbuf[0] + wq * 2048;
#pragma unroll
    for (int j = 0; j < 2; ++j) {
      __builtin_amdgcn_global_load_lds((gas1_t)(const void*)(kgl + (size_t)(j * 8) * DD),
                                       (las3_t)(void*)(kd + j * 1024), 16, 0, 0);
      __builtin_amdgcn_global_load_lds((gas1_t)(const void*)(vgl + (size_t)(j * 8) * SS),
                                       (las3_t)(void*)(vd + j * 1024), 16, 0, 0);
    }
  }
  f16x8 bbr[4], bbn[4];
#pragma unroll
  for (int g = 0; g < 4; ++g)
    bbr[g] = *(const f16x8*)(btile + g * 2048);
  __syncthreads();

  f32x16 o0 = {}, o1 = {};
  float m = -1e30f, lsum = 0.f;
  int cur = 0;

  for (int kt = 0; kt < 16; ++kt) {
    if (kt < 15) {
      char* kd = (char*)kbuf[cur ^ 1] + wq * 2048;
      char* vd = (char*)vbuf[cur ^ 1] + wq * 2048;
      const size_t k1 = (size_t)(kt + 1) * 64;
#pragma unroll
      for (int j = 0; j < 2; ++j) {
        __builtin_amdgcn_global_load_lds((gas1_t)(const void*)(kgl + (k1 + j * 8) * DD),
                                         (las3_t)(void*)(kd + j * 1024), 16, 0, 0);
        __builtin_amdgcn_global_load_lds((gas1_t)(const void*)(vgl + (size_t)(j * 8) * SS + k1),
                                         (las3_t)(void*)(vd + j * 1024), 16, 0, 0);
      }
      const _Float16* bt = btile + ((size_t)(kt + 1) << 13);
#pragma unroll
      for (int g = 0; g < 4; ++g)
        bbn[g] = *(const f16x8*)(bt + g * 2048);
    }

    const char* kb_base = (const char*)kbuf[cur];
    f32x16 s[2];
#pragma unroll
    for (int kb = 0; kb < 2; ++kb) {
      f32x16 acc = {};
#pragma unroll
      for (int d = 0; d < 4; ++d) {
        bf16x8 kf = *(const bf16x8*)(kb_base + (kb * 32 + ln) * 128 + (((u32)(d * 32 + hi * 16)) ^ swz));
        acc = MFMA32(kf, qf[d], acc);
      }
      s[kb] = acc;
    }

#pragma unroll
    for (int g = 0; g < 4; ++g) {
      const int kb = g >> 1, rq0 = (g & 1) * 2;
#pragma unroll
      for (int e = 0; e < 8; ++e)
        s[kb][(rq0 + (e >> 2)) * 4 + (e & 3)] =
            fmaf(s[kb][(rq0 + (e >> 2)) * 4 + (e & 3)], 0.03125f, (float)bbr[g][e]);
    }

    float mt = -1e30f;
#pragma unroll
    for (int r = 0; r < 16; ++r) { mt = fmaxf(mt, s[0][r]); mt = fmaxf(mt, s[1][r]); }
    mt = fmaxf(mt, __shfl_xor(mt, 32));

    bool resc = false;
    float fsc = 1.f;
    if (kt == 0) {
      m = mt;
    } else if (__any(mt > m + 8.f)) {
      float mn = fmaxf(m, mt);
      fsc = __expf(m - mn);
      m = mn;
      resc = true;
    }

    float rs = 0.f;
    u32 wv[2][8];
#pragma unroll
    for (int kb = 0; kb < 2; ++kb)
#pragma unroll
      for (int t = 0; t < 8; ++t) {
        float p0 = __expf(s[kb][2 * t] - m);
        float p1 = __expf(s[kb][2 * t + 1] - m);
        rs += p0 + p1;
        wv[kb][t] = pk2(p0, p1);
      }
    rs += __shfl_xor(rs, 32);
    lsum = lsum * fsc + rs;

    if (resc) {
#pragma unroll
      for (int j = 0; j < 16; ++j) {
        float fv = __shfl(fsc, (j & 3) + 8 * (j >> 2) + 4 * hi);
        o0[j] *= fv; o1[j] *= fv;
      }
    }

    const char* vb_base = (const char*)vbuf[cur];
#pragma unroll
    for (int ks = 0; ks < 4; ++ks) {
      const int kb = ks >> 1, i0 = (ks & 1) * 4;
      u32 sA = hi ? wv[kb][i0 + 0] : wv[kb][i0 + 2];
      u32 sB = hi ? wv[kb][i0 + 1] : wv[kb][i0 + 3];
      u32 rA = (u32)__shfl_xor((int)sA, 32);
      u32 rB = (u32)__shfl_xor((int)sB, 32);
      u32 e0 = hi ? rA : wv[kb][i0 + 0];
      u32 e1 = hi ? rB : wv[kb][i0 + 1];
      u32 e2 = hi ? wv[kb][i0 + 2] : rA;
      u32 e3 = hi ? wv[kb][i0 + 3] : rB;
      union { u32x4 u; bf16x8 v; } pc;
      pc.u = (u32x4){e0, e1, e2, e3};
      bf16x8 pa = pc.v;
#pragma unroll
      for (int nv = 0; nv < 2; ++nv) {
        bf16x8 vf = *(const bf16x8*)(vb_base + (nv * 32 + ln) * 128 + (((u32)(ks * 32 + hi * 16)) ^ swz));
        if (nv == 0) o0 = MFMA32(pa, vf, o0);
        else         o1 = MFMA32(pa, vf, o1);
      }
    }

    if (kt < 15) {
      __syncthreads();
      cur ^= 1;
#pragma unroll
      for (int g = 0; g < 4; ++g) bbr[g] = bbn[g];
    }
  }

  float inv = 1.0f / lsum;
#pragma unroll
  for (int j = 0; j < 16; ++j) {
    float iv = __shfl(inv, (j & 3) + 8 * (j >> 2) + 4 * hi);
    int q = q0 + wq * 32 + (j & 3) + 8 * (j >> 2) + 4 * hi;
    u16* op = O + (size_t)(b * SS + q) * DD + h * 64 + ln;
    op[0]  = f2b(o0[j] * iv);
    op[32] = f2b(o1[j] * iv);
  }
}

// ---------------- host launch ----------------
extern "C" void kernel_launch(void* const* d_in, const int* in_sizes, int n_in,
                              void* d_out, int out_size, void* d_ws, size_t ws_size,
                              hipStream_t stream) {
  const float* queries = (const float*)d_in[0];
  const float* keys    = (const float*)d_in[1];
  const float* values  = (const float*)d_in[2];
  const float* bias    = (const float*)d_in[3];
  const float* Wq      = (const float*)d_in[4];
  const float* Wk      = (const float*)d_in[5];
  const float* Wv      = (const float*)d_in[6];
  const float* Wp      = (const float*)d_in[7];
  float* out = (float*)d_out;

  char* ws = (char*)d_ws;
  const size_t MB = 1024 * 1024;
  u16* wqb = (u16*)(ws + 24 * MB);   // wqb/wkb/wvb contiguous at 2 MB stride
  u16* wkb = (u16*)(ws + 26 * MB);
  u16* wvb = (u16*)(ws + 28 * MB);
  u16* wpb = (u16*)(ws + 30 * MB);
  u16* Qb  = (u16*)(ws + 32 * MB);
  u16* Kb  = (u16*)(ws + 40 * MB);
  _Float16* bias16 = (_Float16*)(ws + 48 * MB);
  u16* Vtb = (u16*)(ws + 56 * MB);
  u16* Ob  = (u16*)(ws + 0 * MB);

  // weights + bias pack
  cvt_all<<<dim3(6144), dim3(256), 0, stream>>>(
      Wq, Wk, Wv, Wp, bias, wqb, wkb, wvb, wpb, bias16);

  // QKV projections: reg-staged fp32 A -> bf16 LDS (fast inner loop preserved)
  gemm_qkv<<<dim3(8, 32, 3), dim3(512), 0, stream>>>(
      queries, keys, values, wqb, Qb, Kb, Vtb);

  attn_kernel<<<dim3(8, 16, 4), dim3(256), 0, stream>>>(Qb, Kb, Vtb, bias16, Ob);

  gemm_proj<<<dim3(8, 32, 1), dim3(512), 0, stream>>>(Ob, wpb, out, DD, DD);
}